// Round 13
// baseline (51.916 us; speedup 1.0000x reference)
//
#include <hip/hip_runtime.h>
#include <math.h>

// Problem constants (from reference): B=128, C=3, H=256, W=256, fp32.
#define BATCH 128
#define CHAN  3
#define IMH   256
#define IMW   256
#define NXCD  8
#define TW    32   // output tile width  (per tile)
#define TH    16   // output tile height (per tile) -- 2 px per thread in h

// Packed-RGB LDS tile: [row][col*3 + ch]. 42 rows x 44 cols x 3 ch.
// 42*132*4 = 22,176 B -> 7 blocks/CU.
#define BH_T   42
#define NC_MAX 44
#define ROWSTR 132   // NC_MAX * 3

// Persistent grid: 7 blocks/CU x 256 CU = 1792, all co-resident.
// Logical tiles: 16384 = 8 XCD-chunks x 2048; each XCD's 224 blocks split
// their 2048-tile range bijectively into contiguous runs of 9 or 10.
#define PBLK   1792
#define BPX    224    // blocks per XCD
#define TPX    2048   // tiles per XCD
#define QT     9      // TPX / BPX
#define RT     32     // TPX - BPX*QT

// ---------------------------------------------------------------------------
// Persistent fused kernel. Block = 256 threads; loops over 9-10 contiguous
// 32x16 tiles (2 px/thread stacked in h). Per-image params (HW trig) are
// recomputed only when the image index changes (~1.1x per block, vs every
// block before). Pixel-pair math is float2 -> VOP3P packed fp32
// (v_pk_fma_f32), halving weight/gather FMA instruction count.
// ---------------------------------------------------------------------------
__global__ __launch_bounds__(256) void affine_sample_kernel(
        const float* __restrict__ img,
        const float* __restrict__ rot,
        const float* __restrict__ trans,
        const float* __restrict__ scale,
        const float* __restrict__ shear,
        float* __restrict__ out) {
    __shared__ float tile[BH_T * ROWSTR];   // 22,176 B

    const int pxcd = blockIdx.x & (NXCD - 1);
    const int j    = blockIdx.x >> 3;
    const int cnt  = (j < RT) ? (QT + 1) : QT;
    const int off  = (j < RT) ? j * (QT + 1) : RT * (QT + 1) + (j - RT) * QT;
    const int Lbase = pxcd * TPX + off;

    // per-thread invariants
    const int t    = threadIdx.x;
    const int wl   = t & 31;                  // w lane 0..31
    const int hoff = (t >> 5) << 1;           // 0,2,..,14
    const int lx2  = wl << 1;                 // stager col pair 0,2,..,62
    const int lyr  = t >> 5;                  // stager row 0..7 per round
    const int plane = IMH * IMW;

    int bcur = -1;
    float a00 = 0.f, a01 = 0.f, a10 = 0.f, a11 = 0.f;
    float Cx = 0.f, Cy = 0.f, hx = 0.f, hy = 0.f;
    const float* ibase = img;

    for (int k = 0; k < cnt; ++k) {
        const int L  = Lbase + k;
        const int b  = L >> 7;            // 128 tiles per image
        const int tl = L & 127;
        const int w0 = (tl & 7) * TW;
        const int h0 = (tl >> 3) * TH;

        if (b != bcur) {                  // block-uniform; ~1.1x per block
            bcur = b;
            const float r   = rot[b];
            const float s   = scale[b];
            const float shx = shear[2 * b + 0];
            const float shy = shear[2 * b + 1];
            const float txr = trans[2 * b + 0];
            const float tyr = trans[2 * b + 1];
            const float c  = __cosf(r);   // v_cos_f32 (~1e-6 err vs 2e-2 tol)
            const float sn = __sinf(r);
            a00 = s * (c - sn * shy);
            a01 = s * (c * shx - sn);
            a10 = s * (sn + c * shy);
            a11 = s * (sn * shx + c);
            const float g0x = 1.0f / (float)IMW - 1.0f;
            const float g0y = 1.0f / (float)IMH - 1.0f;
            Cx = ((a00 * g0x + a01 * g0y + txr + 1.0f) * (float)IMW - 1.0f) * 0.5f;
            Cy = ((a10 * g0x + a11 * g0y + tyr + 1.0f) * (float)IMH - 1.0f) * 0.5f;
            hx = 15.5f * fabsf(a00) + 7.5f * fabsf(a01);
            hy = 15.5f * fabsf(a10) + 7.5f * fabsf(a11);
            ibase = img + (size_t)(b * CHAN) * plane;
        }

        // --- block-uniform bbox of the input footprint ---------------------
        const float ixc = Cx + a00 * ((float)w0 + 15.5f) + a01 * ((float)h0 + 7.5f);
        const float iyc = Cy + a10 * ((float)w0 + 15.5f) + a11 * ((float)h0 + 7.5f);
        const int xlu = (int)floorf(ixc - hx);
        const int xhu = (int)floorf(ixc + hx) + 1;
        const int ylu = (int)floorf(iyc - hy);
        const int yhu = (int)floorf(iyc + hy) + 1;
        const bool interior = (xlu >= 1) & (xhu <= IMW - 2) &
                              (ylu >= 1) & (yhu <= IMH - 2);

        const int x_lo = min(max(xlu, 0), IMW - 1);
        const int x_hi = min(max(xhu, 0), IMW - 1);
        const int y_lo = min(max(ylu, 0), IMH - 1);
        const int y_hi = min(max(yhu, 0), IMH - 1);
        const int xs  = (x_lo - 1) & ~1;   // even staging origin (may be -2)
        const int ys  = y_lo - 1;          // staging origin      (may be -1)
        const int ncs = x_hi + 2 - xs;
        const int nrs = y_hi + 2 - ys;
        const bool fits = (ncs <= NC_MAX) & (nrs <= BH_T);

        // --- per-thread sample coords: 2 px (h, h+1) as float2 -------------
        const int wq = w0 + wl;
        const int hq = h0 + hoff;
        const float ixa = Cx + a00 * (float)wq + a01 * (float)hq;
        const float iya = Cy + a10 * (float)wq + a11 * (float)hq;
        const float2 ixv = {ixa, ixa + a01};
        const float2 iyv = {iya, iya + a11};
        const float2 x0fv = {floorf(ixv.x), floorf(ixv.y)};
        const float2 y0fv = {floorf(iyv.x), floorf(iyv.y)};
        const float2 wx1v = ixv - x0fv;            // v_pk_add
        const float2 wy1v = iyv - y0fv;
        const float2 onev = {1.0f, 1.0f};
        const float2 wx0v = onev - wx1v;
        const float2 wy0v = onev - wy1v;
        float2 w00v = wx0v * wy0v;                 // v_pk_mul
        float2 w10v = wx1v * wy0v;
        float2 w01v = wx0v * wy1v;
        float2 w11v = wx1v * wy1v;
        if (!interior) {                           // rare, block-uniform
            const bool vx0a = (x0fv.x >= 0.0f) & (x0fv.x <= (float)(IMW - 1));
            const bool vx1a = (x0fv.x >= -1.0f) & (x0fv.x <= (float)(IMW - 2));
            const bool vy0a = (y0fv.x >= 0.0f) & (y0fv.x <= (float)(IMH - 1));
            const bool vy1a = (y0fv.x >= -1.0f) & (y0fv.x <= (float)(IMH - 2));
            if (!(vx0a && vy0a)) w00v.x = 0.0f;
            if (!(vx1a && vy0a)) w10v.x = 0.0f;
            if (!(vx0a && vy1a)) w01v.x = 0.0f;
            if (!(vx1a && vy1a)) w11v.x = 0.0f;
            const bool vx0b = (x0fv.y >= 0.0f) & (x0fv.y <= (float)(IMW - 1));
            const bool vx1b = (x0fv.y >= -1.0f) & (x0fv.y <= (float)(IMW - 2));
            const bool vy0b = (y0fv.y >= 0.0f) & (y0fv.y <= (float)(IMH - 1));
            const bool vy1b = (y0fv.y >= -1.0f) & (y0fv.y <= (float)(IMH - 2));
            if (!(vx0b && vy0b)) w00v.y = 0.0f;
            if (!(vx1b && vy0b)) w10v.y = 0.0f;
            if (!(vx0b && vy1b)) w01v.y = 0.0f;
            if (!(vx1b && vy1b)) w11v.y = 0.0f;
        }
        const int x0ia = (int)x0fv.x, y0ia = (int)y0fv.x;
        const int x0ib = (int)x0fv.y, y0ib = (int)y0fv.y;
        const int obase = (b * CHAN) * plane + hq * IMW + wq;

        // protect LDS from previous tile's readers before re-staging
        if (k) __syncthreads();

        if (fits) {
            // Stager: 32 float2-lanes x 8 rows per round; packed-RGB writes.
            // Interior blocks: zero clamps (bbox proof => in-image).
            // No zero-fill: any tap reading a garbage cell has weight 0.
            const int nrd = (nrs + 7) >> 3;
            const bool wcol = lx2 < ncs;
            if (interior) {
                const float* colp = ibase + (xs + lx2);
                for (int rr = 0; rr < nrd; ++rr) {
                    const int dy = (rr << 3) + lyr;
                    if (wcol & (dy < nrs)) {
                        const float* src = colp + (ys + dy) * IMW;
                        const float2 v0 = *(const float2*)(src);
                        const float2 v1 = *(const float2*)(src + plane);
                        const float2 v2 = *(const float2*)(src + 2 * plane);
                        float* dst = &tile[dy * ROWSTR + lx2 * 3];
                        dst[0] = v0.x; dst[1] = v1.x; dst[2] = v2.x;
                        dst[3] = v0.y; dst[4] = v1.y; dst[5] = v2.y;
                    }
                }
            } else {
                const int xg = min(max(xs + lx2, 0), IMW - 2);
                for (int rr = 0; rr < nrd; ++rr) {
                    const int dy = (rr << 3) + lyr;
                    if (wcol & (dy < nrs)) {
                        const int yg = min(max(ys + dy, 0), IMH - 1);
                        const float* src = ibase + yg * IMW + xg;
                        const float2 v0 = *(const float2*)(src);
                        const float2 v1 = *(const float2*)(src + plane);
                        const float2 v2 = *(const float2*)(src + 2 * plane);
                        float* dst = &tile[dy * ROWSTR + lx2 * 3];
                        dst[0] = v0.x; dst[1] = v1.x; dst[2] = v2.x;
                        dst[3] = v0.y; dst[4] = v1.y; dst[5] = v2.y;
                    }
                }
            }
        }
        __syncthreads();

        if (fits) {
            // Gather from LDS; pixel-pair packed FMA (v_pk_fma_f32).
            int rxa, rya, rxb, ryb;
            if (interior) {
                rxa = x0ia - xs;  rya = y0ia - ys;
                rxb = x0ib - xs;  ryb = y0ib - ys;
            } else {
                rxa = min(max(x0ia - xs, 0), ncs - 2);
                rya = min(max(y0ia - ys, 0), nrs - 2);
                rxb = min(max(x0ib - xs, 0), ncs - 2);
                ryb = min(max(y0ib - ys, 0), nrs - 2);
            }
            const float* tpa = &tile[rya * ROWSTR + rxa * 3];
            const float* tpb = &tile[ryb * ROWSTR + rxb * 3];
#pragma unroll
            for (int cc = 0; cc < CHAN; ++cc) {
                const float2 t00 = {tpa[cc],          tpb[cc]};
                const float2 t10 = {tpa[cc + 3],      tpb[cc + 3]};
                const float2 t01 = {tpa[cc + ROWSTR], tpb[cc + ROWSTR]};
                const float2 t11 = {tpa[cc + ROWSTR + 3], tpb[cc + ROWSTR + 3]};
                const float2 v = w00v * t00 + w10v * t10
                               + w01v * t01 + w11v * t11;
                out[obase + cc * plane]       = v.x;
                out[obase + cc * plane + IMW] = v.y;
            }
        } else {
            // fallback: direct global gathers (extreme rotation/shear tail)
            const int x0ca = min(max(x0ia, 0), IMW - 1);
            const int x1ca = min(max(x0ia + 1, 0), IMW - 1);
            const int y0ca = min(max(y0ia, 0), IMH - 1);
            const int y1ca = min(max(y0ia + 1, 0), IMH - 1);
            const int x0cb = min(max(x0ib, 0), IMW - 1);
            const int x1cb = min(max(x0ib + 1, 0), IMW - 1);
            const int y0cb = min(max(y0ib, 0), IMH - 1);
            const int y1cb = min(max(y0ib + 1, 0), IMH - 1);
#pragma unroll
            for (int cc = 0; cc < CHAN; ++cc) {
                const float* p2 = ibase + cc * plane;
                const float va = w00v.x * p2[y0ca * IMW + x0ca] + w10v.x * p2[y0ca * IMW + x1ca]
                               + w01v.x * p2[y1ca * IMW + x0ca] + w11v.x * p2[y1ca * IMW + x1ca];
                const float vb = w00v.y * p2[y0cb * IMW + x0cb] + w10v.y * p2[y0cb * IMW + x1cb]
                               + w01v.y * p2[y1cb * IMW + x0cb] + w11v.y * p2[y1cb * IMW + x1cb];
                out[obase + cc * plane]       = va;
                out[obase + cc * plane + IMW] = vb;
            }
        }
    }
}

extern "C" void kernel_launch(void* const* d_in, const int* in_sizes, int n_in,
                              void* d_out, int out_size, void* d_ws, size_t ws_size,
                              hipStream_t stream) {
    const float* img   = (const float*)d_in[0];
    const float* rot   = (const float*)d_in[1];
    const float* trans = (const float*)d_in[2];
    const float* scale = (const float*)d_in[3];
    const float* shear = (const float*)d_in[4];
    float* out = (float*)d_out;

    affine_sample_kernel<<<PBLK, 256, 0, stream>>>(img, rot, trans, scale,
                                                   shear, out);
}

// Round 14
// 42.752 us; speedup vs baseline: 1.2143x; 1.2143x over previous
//
#include <hip/hip_runtime.h>
#include <math.h>

// Problem constants (from reference): B=128, C=3, H=256, W=256, fp32.
#define BATCH 128
#define CHAN  3
#define IMH   256
#define IMW   256
#define NXCD  8
#define TW    32   // output tile width  (per block)
#define TH    16   // output tile height (per block) -- 2 px per thread in h

// Packed-RGB LDS tile: [row][col*3 + ch]. 42 rows x 44 cols x 3 ch.
// 42*132*4 = 22,176 B -> 7 blocks/CU.
#define BH_T   42
#define NC_MAX 44
#define ROWSTR 132   // NC_MAX * 3

// ---------------------------------------------------------------------------
// Single fused kernel; one 32x16 tile per block (16384 blocks -- adjacent
// blocks co-resident on one XCD share the image -> L2-friendly; the R13
// persistent-grid variant proved the alternative thrashes L2, FETCH 46->90MB).
// 2 px per thread stacked in h, math packed as float2 -> VOP3P (v_pk_*),
// per-image params via HW trig, packed-RGB LDS, interior-specialized stager.
// ---------------------------------------------------------------------------
__global__ __launch_bounds__(256) void affine_sample_kernel(
        const float* __restrict__ img,
        const float* __restrict__ rot,
        const float* __restrict__ trans,
        const float* __restrict__ scale,
        const float* __restrict__ shear,
        float* __restrict__ out) {
    __shared__ float tile[BH_T * ROWSTR];   // 22,176 B

    const int NBLK = BATCH * (IMH / TH) * (IMW / TW);   // 128*16*8 = 16384
    const int p = blockIdx.x;
    const int L = (p & (NXCD - 1)) * (NBLK / NXCD) + (p >> 3);  // XCD-chunked

    const int b  = L >> 7;            // 128 tiles per image
    const int tl = L & 127;
    const int w0 = (tl & 7) * TW;
    const int h0 = (tl >> 3) * TH;

    // --- per-image params, block-uniform; HW trig --------------------------
    const float r   = rot[b];
    const float s   = scale[b];
    const float shx = shear[2 * b + 0];
    const float shy = shear[2 * b + 1];
    const float txr = trans[2 * b + 0];
    const float tyr = trans[2 * b + 1];
    const float c  = __cosf(r);       // v_cos_f32 (~1e-6 abs err vs 2e-2 tol)
    const float sn = __sinf(r);
    const float a00 = s * (c - sn * shy);
    const float a01 = s * (c * shx - sn);
    const float a10 = s * (sn + c * shy);
    const float a11 = s * (sn * shx + c);
    const float g0x = 1.0f / (float)IMW - 1.0f;   // gx at w=0
    const float g0y = 1.0f / (float)IMH - 1.0f;   // gy at h=0
    const float Cx = ((a00 * g0x + a01 * g0y + txr + 1.0f) * (float)IMW - 1.0f) * 0.5f;
    const float Cy = ((a10 * g0x + a11 * g0y + tyr + 1.0f) * (float)IMH - 1.0f) * 0.5f;
    const float hx = 15.5f * fabsf(a00) + 7.5f * fabsf(a01);
    const float hy = 15.5f * fabsf(a10) + 7.5f * fabsf(a11);

    // --- block-uniform bbox of the input footprint -------------------------
    const float ixc = Cx + a00 * ((float)w0 + 15.5f) + a01 * ((float)h0 + 7.5f);
    const float iyc = Cy + a10 * ((float)w0 + 15.5f) + a11 * ((float)h0 + 7.5f);
    const int xlu = (int)floorf(ixc - hx);        // unclamped
    const int xhu = (int)floorf(ixc + hx) + 1;
    const int ylu = (int)floorf(iyc - hy);
    const int yhu = (int)floorf(iyc + hy) + 1;
    const bool interior = (xlu >= 1) & (xhu <= IMW - 2) & (ylu >= 1) & (yhu <= IMH - 2);

    const int x_lo = min(max(xlu, 0), IMW - 1);
    const int x_hi = min(max(xhu, 0), IMW - 1);
    const int y_lo = min(max(ylu, 0), IMH - 1);
    const int y_hi = min(max(yhu, 0), IMH - 1);
    const int xs  = (x_lo - 1) & ~1;   // even staging origin (may be -2)
    const int ys  = y_lo - 1;          // staging origin      (may be -1)
    const int ncs = x_hi + 2 - xs;     // staged cols
    const int nrs = y_hi + 2 - ys;     // staged rows

    // --- per-thread sample coords: 2 px (h, h+1) as float2 -> v_pk_* -------
    const int t  = threadIdx.x;
    const int wq = w0 + (t & 31);
    const int hq = h0 + ((t >> 5) << 1);          // even row; px at hq, hq+1
    const float ixa = Cx + a00 * (float)wq + a01 * (float)hq;
    const float iya = Cy + a10 * (float)wq + a11 * (float)hq;
    const float2 ixv = {ixa, ixa + a01};
    const float2 iyv = {iya, iya + a11};
    const float2 x0fv = {floorf(ixv.x), floorf(ixv.y)};
    const float2 y0fv = {floorf(iyv.x), floorf(iyv.y)};
    const float2 wx1v = ixv - x0fv;
    const float2 wy1v = iyv - y0fv;
    const float2 onev = {1.0f, 1.0f};
    const float2 wx0v = onev - wx1v;
    const float2 wy0v = onev - wy1v;
    float2 w00v = wx0v * wy0v;
    float2 w10v = wx1v * wy0v;
    float2 w01v = wx0v * wy1v;
    float2 w11v = wx1v * wy1v;
    if (!interior) {                               // rare, block-uniform
        const bool vx0a = (x0fv.x >= 0.0f) & (x0fv.x <= (float)(IMW - 1));
        const bool vx1a = (x0fv.x >= -1.0f) & (x0fv.x <= (float)(IMW - 2));
        const bool vy0a = (y0fv.x >= 0.0f) & (y0fv.x <= (float)(IMH - 1));
        const bool vy1a = (y0fv.x >= -1.0f) & (y0fv.x <= (float)(IMH - 2));
        if (!(vx0a && vy0a)) w00v.x = 0.0f;
        if (!(vx1a && vy0a)) w10v.x = 0.0f;
        if (!(vx0a && vy1a)) w01v.x = 0.0f;
        if (!(vx1a && vy1a)) w11v.x = 0.0f;
        const bool vx0b = (x0fv.y >= 0.0f) & (x0fv.y <= (float)(IMW - 1));
        const bool vx1b = (x0fv.y >= -1.0f) & (x0fv.y <= (float)(IMW - 2));
        const bool vy0b = (y0fv.y >= 0.0f) & (y0fv.y <= (float)(IMH - 1));
        const bool vy1b = (y0fv.y >= -1.0f) & (y0fv.y <= (float)(IMH - 2));
        if (!(vx0b && vy0b)) w00v.y = 0.0f;
        if (!(vx1b && vy0b)) w10v.y = 0.0f;
        if (!(vx0b && vy1b)) w01v.y = 0.0f;
        if (!(vx1b && vy1b)) w11v.y = 0.0f;
    }
    const int x0ia = (int)x0fv.x, y0ia = (int)y0fv.x;
    const int x0ib = (int)x0fv.y, y0ib = (int)y0fv.y;

    const int plane = IMH * IMW;
    const int obase = (b * CHAN) * plane + hq * IMW + wq;
    const float* ibase = img + (size_t)(b * CHAN) * plane;

    // --- staged path iff footprint fits LDS. Block-uniform branch. ---------
    if (ncs <= NC_MAX && nrs <= BH_T) {
        // Stager: 32 float2-lanes (64 cols) x 8 rows per round; packed-RGB.
        // Interior blocks: no clamps (bbox proof => addresses in-image).
        // No zero-fill: any tap that could read a garbage cell has weight 0.
        const int lx2 = (t & 31) << 1;            // 0,2,..,62
        const int lyr = t >> 5;                   // 0..7
        const int nrd = (nrs + 7) >> 3;           // 1..6 row rounds
        const bool wcol = lx2 < ncs;
        if (interior) {
            const float* colp = ibase + (xs + lx2);
            for (int rr = 0; rr < nrd; ++rr) {
                const int dy = (rr << 3) + lyr;
                if (wcol & (dy < nrs)) {
                    const float* src = colp + (ys + dy) * IMW;
                    const float2 v0 = *(const float2*)(src);
                    const float2 v1 = *(const float2*)(src + plane);
                    const float2 v2 = *(const float2*)(src + 2 * plane);
                    float* dst = &tile[dy * ROWSTR + lx2 * 3];
                    dst[0] = v0.x; dst[1] = v1.x; dst[2] = v2.x;
                    dst[3] = v0.y; dst[4] = v1.y; dst[5] = v2.y;
                }
            }
        } else {
            const int xg = min(max(xs + lx2, 0), IMW - 2);   // even
            for (int rr = 0; rr < nrd; ++rr) {
                const int dy = (rr << 3) + lyr;
                if (wcol & (dy < nrs)) {
                    const int yg = min(max(ys + dy, 0), IMH - 1);
                    const float* src = ibase + yg * IMW + xg;
                    const float2 v0 = *(const float2*)(src);
                    const float2 v1 = *(const float2*)(src + plane);
                    const float2 v2 = *(const float2*)(src + 2 * plane);
                    float* dst = &tile[dy * ROWSTR + lx2 * 3];
                    dst[0] = v0.x; dst[1] = v1.x; dst[2] = v2.x;
                    dst[3] = v0.y; dst[4] = v1.y; dst[5] = v2.y;
                }
            }
        }
        __syncthreads();

        // Gather from LDS; pixel-pair packed FMA (v_pk_fma_f32).
        int rxa, rya, rxb, ryb;
        if (interior) {
            rxa = x0ia - xs;  rya = y0ia - ys;
            rxb = x0ib - xs;  ryb = y0ib - ys;
        } else {
            rxa = min(max(x0ia - xs, 0), ncs - 2);
            rya = min(max(y0ia - ys, 0), nrs - 2);
            rxb = min(max(x0ib - xs, 0), ncs - 2);
            ryb = min(max(y0ib - ys, 0), nrs - 2);
        }
        const float* tpa = &tile[rya * ROWSTR + rxa * 3];
        const float* tpb = &tile[ryb * ROWSTR + rxb * 3];
#pragma unroll
        for (int cc = 0; cc < CHAN; ++cc) {
            const float2 t00 = {tpa[cc],              tpb[cc]};
            const float2 t10 = {tpa[cc + 3],          tpb[cc + 3]};
            const float2 t01 = {tpa[cc + ROWSTR],     tpb[cc + ROWSTR]};
            const float2 t11 = {tpa[cc + ROWSTR + 3], tpb[cc + ROWSTR + 3]};
            const float2 v = w00v * t00 + w10v * t10 + w01v * t01 + w11v * t11;
            out[obase + cc * plane]       = v.x;
            out[obase + cc * plane + IMW] = v.y;
        }
    } else {
        // fallback: direct global gathers (extreme rotation/shear tail only)
        const int x0ca = min(max(x0ia, 0), IMW - 1);
        const int x1ca = min(max(x0ia + 1, 0), IMW - 1);
        const int y0ca = min(max(y0ia, 0), IMH - 1);
        const int y1ca = min(max(y0ia + 1, 0), IMH - 1);
        const int x0cb = min(max(x0ib, 0), IMW - 1);
        const int x1cb = min(max(x0ib + 1, 0), IMW - 1);
        const int y0cb = min(max(y0ib, 0), IMH - 1);
        const int y1cb = min(max(y0ib + 1, 0), IMH - 1);
#pragma unroll
        for (int cc = 0; cc < CHAN; ++cc) {
            const float* p2 = ibase + cc * plane;
            const float va = w00v.x * p2[y0ca * IMW + x0ca] + w10v.x * p2[y0ca * IMW + x1ca]
                           + w01v.x * p2[y1ca * IMW + x0ca] + w11v.x * p2[y1ca * IMW + x1ca];
            const float vb = w00v.y * p2[y0cb * IMW + x0cb] + w10v.y * p2[y0cb * IMW + x1cb]
                           + w01v.y * p2[y1cb * IMW + x0cb] + w11v.y * p2[y1cb * IMW + x1cb];
            out[obase + cc * plane]       = va;
            out[obase + cc * plane + IMW] = vb;
        }
    }
}

extern "C" void kernel_launch(void* const* d_in, const int* in_sizes, int n_in,
                              void* d_out, int out_size, void* d_ws, size_t ws_size,
                              hipStream_t stream) {
    const float* img   = (const float*)d_in[0];
    const float* rot   = (const float*)d_in[1];
    const float* trans = (const float*)d_in[2];
    const float* scale = (const float*)d_in[3];
    const float* shear = (const float*)d_in[4];
    float* out = (float*)d_out;

    const int nblocks = BATCH * (IMH / TH) * (IMW / TW);   // 16384
    affine_sample_kernel<<<nblocks, 256, 0, stream>>>(img, rot, trans, scale,
                                                      shear, out);
}

// Round 15
// 38.873 us; speedup vs baseline: 1.3355x; 1.0998x over previous
//
#include <hip/hip_runtime.h>
#include <math.h>

// Problem constants (from reference): B=128, C=3, H=256, W=256, fp32.
#define BATCH 128
#define CHAN  3
#define IMH   256
#define IMW   256
#define NXCD  8
#define TW    32   // output tile width  (per block)
#define TH    16   // output tile height (per block) -- 2 px per thread in h

// Planar LDS: 3 channels x [40 rows x 44 cols] (row stride 44 dwords).
// Per-channel stride 1792 dwords = 7 x 256-dword DMA chunks exactly ->
// global_load_lds chunks can never spill into the next channel (no race).
// 3*1792*4 = 21,504 B -> 7 blocks/CU.
#define BH_T   40
#define NC_MAX 44
#define CH_STR 1792

typedef unsigned int u32;

// ---------------------------------------------------------------------------
// Single fused kernel; one 32x16 tile per block (16384 blocks, XCD-chunked).
// 2 px per thread stacked in h; pixel-pair math packed as float2 (v_pk_*);
// per-image params via HW trig. NEW: staging via __builtin_amdgcn_global_load_lds
// width=16 (HBM->LDS DMA): per wave ~6 issue instrs replace ~28 mem-pipe
// instrs (loads + ds_writes); staging LDS writes leave the issue stream.
// DMA dest is wave-uniform base + lane*16 (linear), so LDS is planar; the
// per-lane GLOBAL address carries the (row,col) mapping. Images 0 and 127
// use the old clamped register stager (DMA overreach must stay in-buffer).
// ---------------------------------------------------------------------------
__global__ __launch_bounds__(256) void affine_sample_kernel(
        const float* __restrict__ img,
        const float* __restrict__ rot,
        const float* __restrict__ trans,
        const float* __restrict__ scale,
        const float* __restrict__ shear,
        float* __restrict__ out) {
    __shared__ float tile[CHAN * CH_STR];   // 21,504 B

    const int NBLK = BATCH * (IMH / TH) * (IMW / TW);   // 128*16*8 = 16384
    const int p = blockIdx.x;
    const int L = (p & (NXCD - 1)) * (NBLK / NXCD) + (p >> 3);  // XCD-chunked

    const int b  = L >> 7;            // 128 tiles per image
    const int tl = L & 127;
    const int w0 = (tl & 7) * TW;
    const int h0 = (tl >> 3) * TH;

    // --- per-image params, block-uniform; HW trig --------------------------
    const float r   = rot[b];
    const float s   = scale[b];
    const float shx = shear[2 * b + 0];
    const float shy = shear[2 * b + 1];
    const float txr = trans[2 * b + 0];
    const float tyr = trans[2 * b + 1];
    const float c  = __cosf(r);       // v_cos_f32 (~1e-6 abs err vs 2e-2 tol)
    const float sn = __sinf(r);
    const float a00 = s * (c - sn * shy);
    const float a01 = s * (c * shx - sn);
    const float a10 = s * (sn + c * shy);
    const float a11 = s * (sn * shx + c);
    const float g0x = 1.0f / (float)IMW - 1.0f;   // gx at w=0
    const float g0y = 1.0f / (float)IMH - 1.0f;   // gy at h=0
    const float Cx = ((a00 * g0x + a01 * g0y + txr + 1.0f) * (float)IMW - 1.0f) * 0.5f;
    const float Cy = ((a10 * g0x + a11 * g0y + tyr + 1.0f) * (float)IMH - 1.0f) * 0.5f;
    const float hx = 15.5f * fabsf(a00) + 7.5f * fabsf(a01);
    const float hy = 15.5f * fabsf(a10) + 7.5f * fabsf(a11);

    // --- block-uniform bbox of the input footprint -------------------------
    const float ixc = Cx + a00 * ((float)w0 + 15.5f) + a01 * ((float)h0 + 7.5f);
    const float iyc = Cy + a10 * ((float)w0 + 15.5f) + a11 * ((float)h0 + 7.5f);
    const int xlu = (int)floorf(ixc - hx);        // unclamped
    const int xhu = (int)floorf(ixc + hx) + 1;
    const int ylu = (int)floorf(iyc - hy);
    const int yhu = (int)floorf(iyc + hy) + 1;
    const bool interior = (xlu >= 1) & (xhu <= IMW - 2) & (ylu >= 1) & (yhu <= IMH - 2);

    const int x_lo = min(max(xlu, 0), IMW - 1);
    const int x_hi = min(max(xhu, 0), IMW - 1);
    const int y_lo = min(max(ylu, 0), IMH - 1);
    const int y_hi = min(max(yhu, 0), IMH - 1);
    const int xs  = (x_lo - 1) & ~1;   // even staging origin (may be -2)
    const int ys  = y_lo - 1;          // staging origin      (may be -1)
    const int ncs = x_hi + 2 - xs;     // staged cols
    const int nrs = y_hi + 2 - ys;     // staged rows

    // --- per-thread sample coords: 2 px (h, h+1) as float2 -> v_pk_* -------
    const int t  = threadIdx.x;
    const int wq = w0 + (t & 31);
    const int hq = h0 + ((t >> 5) << 1);          // even row; px at hq, hq+1
    const float ixa = Cx + a00 * (float)wq + a01 * (float)hq;
    const float iya = Cy + a10 * (float)wq + a11 * (float)hq;
    const float2 ixv = {ixa, ixa + a01};
    const float2 iyv = {iya, iya + a11};
    const float2 x0fv = {floorf(ixv.x), floorf(ixv.y)};
    const float2 y0fv = {floorf(iyv.x), floorf(iyv.y)};
    const float2 wx1v = ixv - x0fv;
    const float2 wy1v = iyv - y0fv;
    const float2 onev = {1.0f, 1.0f};
    const float2 wx0v = onev - wx1v;
    const float2 wy0v = onev - wy1v;
    float2 w00v = wx0v * wy0v;
    float2 w10v = wx1v * wy0v;
    float2 w01v = wx0v * wy1v;
    float2 w11v = wx1v * wy1v;
    if (!interior) {                               // rare, block-uniform
        const bool vx0a = (x0fv.x >= 0.0f) & (x0fv.x <= (float)(IMW - 1));
        const bool vx1a = (x0fv.x >= -1.0f) & (x0fv.x <= (float)(IMW - 2));
        const bool vy0a = (y0fv.x >= 0.0f) & (y0fv.x <= (float)(IMH - 1));
        const bool vy1a = (y0fv.x >= -1.0f) & (y0fv.x <= (float)(IMH - 2));
        if (!(vx0a && vy0a)) w00v.x = 0.0f;
        if (!(vx1a && vy0a)) w10v.x = 0.0f;
        if (!(vx0a && vy1a)) w01v.x = 0.0f;
        if (!(vx1a && vy1a)) w11v.x = 0.0f;
        const bool vx0b = (x0fv.y >= 0.0f) & (x0fv.y <= (float)(IMW - 1));
        const bool vx1b = (x0fv.y >= -1.0f) & (x0fv.y <= (float)(IMW - 2));
        const bool vy0b = (y0fv.y >= 0.0f) & (y0fv.y <= (float)(IMH - 1));
        const bool vy1b = (y0fv.y >= -1.0f) & (y0fv.y <= (float)(IMH - 2));
        if (!(vx0b && vy0b)) w00v.y = 0.0f;
        if (!(vx1b && vy0b)) w10v.y = 0.0f;
        if (!(vx0b && vy1b)) w01v.y = 0.0f;
        if (!(vx1b && vy1b)) w11v.y = 0.0f;
    }
    const int x0ia = (int)x0fv.x, y0ia = (int)y0fv.x;
    const int x0ib = (int)x0fv.y, y0ib = (int)y0fv.y;

    const int plane = IMH * IMW;
    const int obase = (b * CHAN) * plane + hq * IMW + wq;
    const float* ibase = img + (size_t)(b * CHAN) * plane;

    // --- staged path iff footprint fits LDS. Block-uniform branch. ---------
    if (ncs <= NC_MAX && nrs <= BH_T) {
        const bool dma = (b > 0) & (b < BATCH - 1);   // DMA overreach stays in-buffer
        if (dma) {
            // HBM->LDS DMA stager. Chunk = 256 dwords (wave64 x 16B).
            // Per channel: Nch = ceil(nrs*44/256) <= 7 chunks; wave w issues
            // chunks w, w+4, ... Per-lane global addr maps its 4 dwords to
            // (row = idx/44, col = idx%44); col%4==0 so the 16B never spans
            // a row boundary. No clamps: out-of-range rows/cols read garbage
            // from adjacent planes (in-buffer); those LDS cells are only
            // reachable through weight-0 taps.
            const int wid  = t >> 6;            // wave 0..3
            const int lane = t & 63;
            int idx = (wid << 8) + (lane << 2);
            int row = idx / 44;                  // magic-mul div, once
            int col = idx - row * 44;
            const int Nch  = (nrs * 44 + 255) >> 8;
            const int soff = ys * IMW + xs;      // block-uniform
            for (int j = wid; j < Nch; j += 4) {
                const int off = soff + row * IMW + col;
#pragma unroll
                for (int cc = 0; cc < CHAN; ++cc) {
                    const float* gp = ibase + cc * plane + off;
                    __builtin_amdgcn_global_load_lds(
                        (const __attribute__((address_space(1))) u32*)(const void*)gp,
                        (__attribute__((address_space(3))) u32*)(void*)
                            &tile[cc * CH_STR + (j << 8)],
                        16, 0, 0);
                }
                row += 23; col += 12;            // idx += 1024
                const int wr = (col >= 44) ? 1 : 0;
                col -= wr * 44; row += wr;
            }
        } else {
            // Register stager with full clamping (first/last image only).
            const int lx2 = (t & 31) << 1;       // 0,2,..,62
            const int lyr = t >> 5;              // 0..7
            const int nrd = (nrs + 7) >> 3;      // 1..5 rounds
            const bool wcol = lx2 < ncs;
            const int xg = min(max(xs + lx2, 0), IMW - 2);   // even
            for (int rr = 0; rr < nrd; ++rr) {
                const int dy = (rr << 3) + lyr;
                if (wcol & (dy < nrs)) {
                    const int yg = min(max(ys + dy, 0), IMH - 1);
                    const float* src = ibase + yg * IMW + xg;
                    const float2 v0 = *(const float2*)(src);
                    const float2 v1 = *(const float2*)(src + plane);
                    const float2 v2 = *(const float2*)(src + 2 * plane);
                    float* d0 = &tile[dy * NC_MAX + lx2];
                    d0[0] = v0.x;               d0[1] = v0.y;
                    d0[CH_STR] = v1.x;          d0[CH_STR + 1] = v1.y;
                    d0[2 * CH_STR] = v2.x;      d0[2 * CH_STR + 1] = v2.y;
                }
            }
        }
        __syncthreads();   // drains vmcnt (DMA) + lgkm before gather

        // Gather from planar LDS; pixel-pair packed FMA (v_pk_fma_f32).
        int rxa, rya, rxb, ryb;
        if (interior) {
            rxa = x0ia - xs;  rya = y0ia - ys;
            rxb = x0ib - xs;  ryb = y0ib - ys;
        } else {
            rxa = min(max(x0ia - xs, 0), ncs - 2);
            rya = min(max(y0ia - ys, 0), nrs - 2);
            rxb = min(max(x0ib - xs, 0), ncs - 2);
            ryb = min(max(y0ib - ys, 0), nrs - 2);
        }
        const int la = rya * NC_MAX + rxa;
        const int lb = ryb * NC_MAX + rxb;
#pragma unroll
        for (int cc = 0; cc < CHAN; ++cc) {
            const float* pa = &tile[cc * CH_STR + la];
            const float* pb = &tile[cc * CH_STR + lb];
            const float2 t00 = {pa[0],          pb[0]};
            const float2 t10 = {pa[1],          pb[1]};
            const float2 t01 = {pa[NC_MAX],     pb[NC_MAX]};
            const float2 t11 = {pa[NC_MAX + 1], pb[NC_MAX + 1]};
            const float2 v = w00v * t00 + w10v * t10 + w01v * t01 + w11v * t11;
            out[obase + cc * plane]       = v.x;
            out[obase + cc * plane + IMW] = v.y;
        }
    } else {
        // fallback: direct global gathers (extreme rotation/shear tail only)
        const int x0ca = min(max(x0ia, 0), IMW - 1);
        const int x1ca = min(max(x0ia + 1, 0), IMW - 1);
        const int y0ca = min(max(y0ia, 0), IMH - 1);
        const int y1ca = min(max(y0ia + 1, 0), IMH - 1);
        const int x0cb = min(max(x0ib, 0), IMW - 1);
        const int x1cb = min(max(x0ib + 1, 0), IMW - 1);
        const int y0cb = min(max(y0ib, 0), IMH - 1);
        const int y1cb = min(max(y0ib + 1, 0), IMH - 1);
#pragma unroll
        for (int cc = 0; cc < CHAN; ++cc) {
            const float* p2 = ibase + cc * plane;
            const float va = w00v.x * p2[y0ca * IMW + x0ca] + w10v.x * p2[y0ca * IMW + x1ca]
                           + w01v.x * p2[y1ca * IMW + x0ca] + w11v.x * p2[y1ca * IMW + x1ca];
            const float vb = w00v.y * p2[y0cb * IMW + x0cb] + w10v.y * p2[y0cb * IMW + x1cb]
                           + w01v.y * p2[y1cb * IMW + x0cb] + w11v.y * p2[y1cb * IMW + x1cb];
            out[obase + cc * plane]       = va;
            out[obase + cc * plane + IMW] = vb;
        }
    }
}

extern "C" void kernel_launch(void* const* d_in, const int* in_sizes, int n_in,
                              void* d_out, int out_size, void* d_ws, size_t ws_size,
                              hipStream_t stream) {
    const float* img   = (const float*)d_in[0];
    const float* rot   = (const float*)d_in[1];
    const float* trans = (const float*)d_in[2];
    const float* scale = (const float*)d_in[3];
    const float* shear = (const float*)d_in[4];
    float* out = (float*)d_out;

    const int nblocks = BATCH * (IMH / TH) * (IMW / TW);   // 16384
    affine_sample_kernel<<<nblocks, 256, 0, stream>>>(img, rot, trans, scale,
                                                      shear, out);
}